// Round 1
// baseline (290.029 us; speedup 1.0000x reference)
//
#include <hip/hip_runtime.h>

typedef _Float16 f16;
typedef _Float16 f16x2 __attribute__((ext_vector_type(2)));
typedef _Float16 f16x4 __attribute__((ext_vector_type(4)));
typedef _Float16 f16x8 __attribute__((ext_vector_type(8)));
typedef float    f32x4 __attribute__((ext_vector_type(4)));

// Geometry:
//   x:   (4,128,64,64) f32     p5: (128,21,64,64) f32
//   p6:  (128,21,128)  f32     out:(4,128,64,64)  f32
// Workspace:
//   xk[kc][n][c][row 0..81][w 0..63] f16 = x[n][c][row-9][w+2*kc-2] * 0.125 (zero padded)
//   t6T[n][d][k2=rk*128+c] f16 = p6[c][rk][d] * t3[n][c][rk][d]
#define XROWS 82
#define XSTR  (XROWS * 64)                    // 5248 f16 per (kc,n,c) plane
#define XK_ELEMS (3u * 4u * 128u * (unsigned)XSTR)
static const size_t T6T_OFF = (size_t)XK_ELEMS * 2;  // bytes; t6T = 4*128*2688 f16

// ---------------------------------------------------------------- prep
__global__ __launch_bounds__(256) void prep_kernel(const float* __restrict__ x,
                                                   f16* __restrict__ xk) {
  unsigned p = blockIdx.x * 256u + threadIdx.x;           // f16x2 index
  unsigned total = 3u * 4u * 128u * 82u * 32u;
  if (p >= total) return;
  unsigned wp   = p & 31u;
  unsigned row  = (p >> 5) % 82u;
  unsigned rest = p / (32u * 82u);
  unsigned c    = rest & 127u;
  unsigned rest2 = rest >> 7;
  unsigned n    = rest2 & 3u;
  unsigned kc   = rest2 >> 2;
  int hsrc = (int)row - 9;
  int wsrc = (int)(wp * 2u) + 2 * (int)kc - 2;
  f16x2 v; v.x = (f16)0.f; v.y = (f16)0.f;
  if (hsrc >= 0 && hsrc < 64 && wsrc >= 0 && wsrc < 64) {
    const float2* src = (const float2*)(x + (((size_t)(n * 128u + c) * 64u + (unsigned)hsrc) * 64u + (unsigned)wsrc));
    float2 xv = *src;
    v.x = (f16)(xv.x * 0.125f);
    v.y = (f16)(xv.y * 0.125f);
  }
  ((f16x2*)xk)[p] = v;
}

// ---------------------------------------------------------------- gram (t3 -> t6T)
// grid 168 = n(4) * rk(21) * cseg(2); block 256 (4 waves, 2x2), WG tile 64c x 128d, K=4096
__global__ __launch_bounds__(256) void gram_kernel(const f16* __restrict__ xk,
                                                   const float* __restrict__ p6,
                                                   f16* __restrict__ t6T) {
  unsigned b    = blockIdx.x;
  unsigned cseg = b & 1u;
  unsigned rk   = (b >> 1) % 21u;
  unsigned n    = b / 42u;
  unsigned r    = rk / 3u;
  unsigned kc   = rk - r * 3u;

  unsigned tid  = threadIdx.x;
  unsigned wv   = tid >> 6;
  unsigned lane = tid & 63u;
  unsigned wy   = wv >> 1;      // c 32-half within cseg
  unsigned wx   = wv & 1u;      // d 64-half
  unsigned quad = lane >> 4;
  unsigned l16  = lane & 15u;

  f32x4 acc[2][4] = {};

  const f16* Abase = xk + (size_t)(kc * 4u + n) * 128u * XSTR;
  const f16* Bbase = xk + (size_t)(1u * 4u + n) * 128u * XSTR;
  unsigned cA = cseg * 64u + wy * 32u + l16;
  unsigned dB = wx * 64u + l16;
  const f16* Ap[2];
  const f16* Bp[4];
#pragma unroll
  for (int ms = 0; ms < 2; ms++) Ap[ms] = Abase + (size_t)(cA + ms * 16u) * XSTR;
#pragma unroll
  for (int ns = 0; ns < 4; ns++) Bp[ns] = Bbase + (size_t)(dB + ns * 16u) * XSTR;

  for (unsigned h = 0; h < 64u; h++) {
    unsigned Aoff = (h + 3u * r) * 64u;
    unsigned Boff = (h + 9u) * 64u;
#pragma unroll
    for (unsigned wh = 0; wh < 64u; wh += 32u) {
      unsigned koff = wh + quad * 8u;
      f16x8 a[2], bf[4];
#pragma unroll
      for (int ms = 0; ms < 2; ms++) a[ms] = *(const f16x8*)(Ap[ms] + Aoff + koff);
#pragma unroll
      for (int ns = 0; ns < 4; ns++) bf[ns] = *(const f16x8*)(Bp[ns] + Boff + koff);
#pragma unroll
      for (int ms = 0; ms < 2; ms++)
#pragma unroll
        for (int ns = 0; ns < 4; ns++)
          acc[ms][ns] = __builtin_amdgcn_mfma_f32_16x16x32_f16(a[ms], bf[ns], acc[ms][ns], 0, 0, 0);
    }
  }

  // epilogue: t6 = p6 * t3, store transposed t6T[n][d][rk*128+c]
#pragma unroll
  for (int ms = 0; ms < 2; ms++) {
#pragma unroll
    for (int ns = 0; ns < 4; ns++) {
      unsigned c0 = cseg * 64u + wy * 32u + (unsigned)ms * 16u + quad * 4u;
      unsigned d  = wx * 64u + (unsigned)ns * 16u + l16;
      f16x4 o;
#pragma unroll
      for (int reg = 0; reg < 4; reg++) {
        unsigned c = c0 + (unsigned)reg;
        float pv = p6[((size_t)c * 21u + rk) * 128u + d];
        o[reg] = (f16)(acc[ms][ns][reg] * pv);
      }
      *(f16x4*)(t6T + ((size_t)(n * 128u + d) * 2688u + rk * 128u + c0)) = o;
    }
  }
}

// ---------------------------------------------------------------- out (t8)
// grid 256 = n(4) * h(64); block 256 (4 waves, 2x2), WG tile 64w x 128d, K=2688 in 84 chunks of 32
#define ALDS_STR 40   // f16 row stride: 80 B = 16B-aligned, even bank spread
__global__ __launch_bounds__(256) void out_kernel(const f16* __restrict__ xk,
                                                  const float* __restrict__ p5,
                                                  const f16* __restrict__ t6T,
                                                  float* __restrict__ out) {
  unsigned b = blockIdx.x;
  unsigned h = b & 63u;
  unsigned n = b >> 6;

  __shared__ f16 Alds[64 * ALDS_STR];

  unsigned tid  = threadIdx.x;
  unsigned wv   = tid >> 6;
  unsigned lane = tid & 63u;
  unsigned wy   = wv >> 1;     // w 32-half
  unsigned wx   = wv & 1u;     // d 64-half
  unsigned quad = lane >> 4;
  unsigned l16  = lane & 15u;
  unsigned wst  = tid & 63u;   // staging w
  unsigned g    = tid >> 6;    // staging granule (8 c's)

  f32x4 acc[2][4] = {};

  for (unsigned kb = 0; kb < 84u; kb++) {
    unsigned rk = kb >> 2;
    unsigned c0 = (kb & 3u) * 32u;
    unsigned r  = rk / 3u;
    unsigned kc = rk - r * 3u;

    __syncthreads();   // protect previous chunk's Alds reads
    {
      const f16*  xrow = xk + (((size_t)(kc * 4u + n) * 128u + c0 + g * 8u) * XROWS + (h + 3u * r)) * 64u + wst;
      const float* prow = p5 + ((size_t)(c0 + g * 8u) * 21u + rk) * 4096u + h * 64u + wst;
      f16x8 av;
#pragma unroll
      for (int j = 0; j < 8; j++) {
        float xv = (float)xrow[(size_t)j * XSTR];
        float pv = prow[(size_t)j * (21u * 4096u)];
        av[j] = (f16)(xv * (1.0f + pv));
      }
      *(f16x8*)&Alds[wst * ALDS_STR + g * 8u] = av;
    }
    __syncthreads();

    f16x8 a[2], bf[4];
#pragma unroll
    for (int ms = 0; ms < 2; ms++)
      a[ms] = *(const f16x8*)&Alds[(wy * 32u + (unsigned)ms * 16u + l16) * ALDS_STR + quad * 8u];
#pragma unroll
    for (int ns = 0; ns < 4; ns++)
      bf[ns] = *(const f16x8*)(t6T + ((size_t)(n * 128u + wx * 64u + (unsigned)ns * 16u + l16) * 2688u + kb * 32u + quad * 8u));
#pragma unroll
    for (int ms = 0; ms < 2; ms++)
#pragma unroll
      for (int ns = 0; ns < 4; ns++)
        acc[ms][ns] = __builtin_amdgcn_mfma_f32_16x16x32_f16(a[ms], bf[ns], acc[ms][ns], 0, 0, 0);
  }

  const float FS = 0.15430334996209192f;  // 8 / sqrt(2688)
#pragma unroll
  for (int ms = 0; ms < 2; ms++) {
#pragma unroll
    for (int ns = 0; ns < 4; ns++) {
      unsigned w0 = wy * 32u + (unsigned)ms * 16u + quad * 4u;
      unsigned d  = wx * 64u + (unsigned)ns * 16u + l16;
      f32x4 o = acc[ms][ns] * FS;
      *(f32x4*)(out + ((size_t)(n * 128u + d) * 64u + h) * 64u + w0) = o;
    }
  }
}

// ---------------------------------------------------------------- launch
extern "C" void kernel_launch(void* const* d_in, const int* in_sizes, int n_in,
                              void* d_out, int out_size, void* d_ws, size_t ws_size,
                              hipStream_t stream) {
  const float* x  = (const float*)d_in[0];
  const float* p5 = (const float*)d_in[1];
  const float* p6 = (const float*)d_in[2];
  float* out = (float*)d_out;
  f16* xk  = (f16*)((char*)d_ws);
  f16* t6T = (f16*)((char*)d_ws + T6T_OFF);

  unsigned prep_blocks = (3u * 4u * 128u * 82u * 32u + 255u) / 256u;  // 15744
  hipLaunchKernelGGL(prep_kernel, dim3(prep_blocks), dim3(256), 0, stream, x, xk);
  hipLaunchKernelGGL(gram_kernel, dim3(168), dim3(256), 0, stream, xk, p6, t6T);
  hipLaunchKernelGGL(out_kernel,  dim3(256), dim3(256), 0, stream, xk, p5, t6T, out);
}

// Round 2
// 235.329 us; speedup vs baseline: 1.2324x; 1.2324x over previous
//
#include <hip/hip_runtime.h>

typedef _Float16 f16;
typedef _Float16 f16x2 __attribute__((ext_vector_type(2)));
typedef _Float16 f16x4 __attribute__((ext_vector_type(4)));
typedef _Float16 f16x8 __attribute__((ext_vector_type(8)));
typedef float    f32x4 __attribute__((ext_vector_type(4)));

// Geometry:
//   x:   (4,128,64,64) f32     p5: (128,21,64,64) f32
//   p6:  (128,21,128)  f32     out:(4,128,64,64)  f32
// Workspace layout (bytes):
//   xk  [3][4][128][82][64] f16  = x*(1/8), pre-shifted per kc, zero-padded rows
//   t6T [4][128][2688]      f16  = p6 * t3, d-major (B^T for out GEMM)
//   t3  [4][21][128][128]   f32  = split-K accumulator for gram
#define XROWS 82
#define XSTR  (XROWS * 64)                       // 5248 f16 per (kc,n,c) plane
#define XK_ELEMS (3u * 4u * 128u * (unsigned)XSTR)
static const size_t T6T_OFF = (size_t)XK_ELEMS * 2;                 // 16.1 MB
static const size_t T6T_BYTES = (size_t)4 * 128 * 2688 * 2;         // 2.75 MB
static const size_t T3_OFF  = T6T_OFF + T6T_BYTES;
static const size_t T3_BYTES = (size_t)4 * 21 * 128 * 128 * 4;      // 5.5 MB

// ---------------------------------------------------------------- prep
__global__ __launch_bounds__(256) void prep_kernel(const float* __restrict__ x,
                                                   f16* __restrict__ xk) {
  unsigned p = blockIdx.x * 256u + threadIdx.x;           // f16x2 index
  unsigned total = 3u * 4u * 128u * 82u * 32u;
  if (p >= total) return;
  unsigned wp   = p & 31u;
  unsigned row  = (p >> 5) % 82u;
  unsigned rest = p / (32u * 82u);
  unsigned c    = rest & 127u;
  unsigned rest2 = rest >> 7;
  unsigned n    = rest2 & 3u;
  unsigned kc   = rest2 >> 2;
  int hsrc = (int)row - 9;
  int wsrc = (int)(wp * 2u) + 2 * (int)kc - 2;
  f16x2 v; v.x = (f16)0.f; v.y = (f16)0.f;
  if (hsrc >= 0 && hsrc < 64 && wsrc >= 0 && wsrc < 64) {
    const float2* src = (const float2*)(x + (((size_t)(n * 128u + c) * 64u + (unsigned)hsrc) * 64u + (unsigned)wsrc));
    float2 xv = *src;
    v.x = (f16)(xv.x * 0.125f);
    v.y = (f16)(xv.y * 0.125f);
  }
  ((f16x2*)xk)[p] = v;
}

// ---------------------------------------------------------------- gram (split-K -> t3 atomics)
// grid 1344 = n(4) * rk(21) * cseg(2) * ks(8); block 256 (4 waves 2x2), tile 64c x 128d, K-slice = 8 h rows
__global__ __launch_bounds__(256) void gram_kernel(const f16* __restrict__ xk,
                                                   float* __restrict__ t3) {
  unsigned b    = blockIdx.x;
  unsigned ks   = b & 7u;
  unsigned cseg = (b >> 3) & 1u;
  unsigned rk   = (b >> 4) % 21u;
  unsigned n    = b / (16u * 21u);
  unsigned r    = rk / 3u;
  unsigned kc   = rk - r * 3u;

  unsigned tid  = threadIdx.x;
  unsigned wv   = tid >> 6;
  unsigned lane = tid & 63u;
  unsigned wy   = wv >> 1;      // c 32-half within cseg
  unsigned wx   = wv & 1u;      // d 64-half
  unsigned quad = lane >> 4;
  unsigned l16  = lane & 15u;

  f32x4 acc[2][4] = {};

  const f16* Abase = xk + (size_t)(kc * 4u + n) * 128u * XSTR;
  const f16* Bbase = xk + (size_t)(1u * 4u + n) * 128u * XSTR;
  unsigned cA = cseg * 64u + wy * 32u + l16;
  unsigned dB = wx * 64u + l16;
  const f16* Ap[2];
  const f16* Bp[4];
#pragma unroll
  for (int ms = 0; ms < 2; ms++) Ap[ms] = Abase + (size_t)(cA + ms * 16u) * XSTR;
#pragma unroll
  for (int ns = 0; ns < 4; ns++) Bp[ns] = Bbase + (size_t)(dB + ns * 16u) * XSTR;

  unsigned h0 = ks * 8u;
  for (unsigned h = h0; h < h0 + 8u; h++) {
    unsigned Aoff = (h + 3u * r) * 64u;
    unsigned Boff = (h + 9u) * 64u;
#pragma unroll
    for (unsigned wh = 0; wh < 64u; wh += 32u) {
      unsigned koff = wh + quad * 8u;
      f16x8 a[2], bf[4];
#pragma unroll
      for (int ms = 0; ms < 2; ms++) a[ms] = *(const f16x8*)(Ap[ms] + Aoff + koff);
#pragma unroll
      for (int ns = 0; ns < 4; ns++) bf[ns] = *(const f16x8*)(Bp[ns] + Boff + koff);
#pragma unroll
      for (int ms = 0; ms < 2; ms++)
#pragma unroll
        for (int ns = 0; ns < 4; ns++)
          acc[ms][ns] = __builtin_amdgcn_mfma_f32_16x16x32_f16(a[ms], bf[ns], acc[ms][ns], 0, 0, 0);
    }
  }

  // split-K accumulate: t3[n][rk][c][d] += acc  (lanes -> consecutive d: coalesced atomics)
#pragma unroll
  for (int ms = 0; ms < 2; ms++) {
#pragma unroll
    for (int ns = 0; ns < 4; ns++) {
      unsigned c0 = cseg * 64u + wy * 32u + (unsigned)ms * 16u + quad * 4u;
      unsigned d  = wx * 64u + (unsigned)ns * 16u + l16;
#pragma unroll
      for (int reg = 0; reg < 4; reg++) {
        unsigned c = c0 + (unsigned)reg;
        atomicAdd(&t3[(((size_t)n * 21u + rk) * 128u + c) * 128u + d], acc[ms][ns][reg]);
      }
    }
  }
}

// ---------------------------------------------------------------- ep: t6T = p6 * t3 (f16, d-major)
__global__ __launch_bounds__(256) void ep_kernel(const float* __restrict__ t3,
                                                 const float* __restrict__ p6,
                                                 f16* __restrict__ t6T) {
  unsigned idx = blockIdx.x * 256u + threadIdx.x;   // < 344064
  unsigned d   = idx & 127u;
  unsigned c4  = (idx >> 7) & 31u;
  unsigned t   = idx >> 12;                          // n*21+rk, 0..83
  unsigned rk  = t % 21u;
  unsigned n   = t / 21u;
  unsigned c0  = c4 * 4u;
  f16x4 o;
#pragma unroll
  for (int i = 0; i < 4; i++) {
    unsigned c = c0 + (unsigned)i;
    float v = t3[(((size_t)n * 21u + rk) * 128u + c) * 128u + d];
    float pv = p6[((size_t)c * 21u + rk) * 128u + d];
    o[i] = (f16)(v * pv);
  }
  *(f16x4*)(t6T + ((size_t)(n * 128u + d) * 2688u + rk * 128u + c0)) = o;
}

// ---------------------------------------------------------------- out (t8)
// grid 256 = n(4)*h(64); block 1024 = 16 waves = 4 groups x 4 waves.
// Group g owns K-quarter: chunks kb = g + 4*j (j=0..20) => rk=j, c in [g*32, g*32+32).
// Each group stages its own 64w x 32k LDS chunk; register prefetch of chunk j+1;
// 4-phase LDS f32 reduction of the 64x128 tile, coalesced float4 stores.
#define ALDS_STR 40   // f16 row stride (80 B, 16B-aligned)
#define RT_STR   66   // f32 reduce-tile stride (2-way max bank alias)
__global__ __launch_bounds__(1024, 4) void out_kernel(const f16* __restrict__ xk,
                                                      const float* __restrict__ p5,
                                                      const f16* __restrict__ t6T,
                                                      float* __restrict__ out) {
  unsigned b = blockIdx.x;
  unsigned h = b & 63u;
  unsigned n = b >> 6;

  __shared__ float smem[128 * RT_STR];   // 33792 B; aliased: staging (20 KB) then reduce tile
  f16* Alds = (f16*)smem;

  unsigned tid   = threadIdx.x;
  unsigned wv    = tid >> 6;
  unsigned group = wv >> 2;      // K-quarter owner
  unsigned wsub  = wv & 3u;
  unsigned lane  = tid & 63u;
  unsigned wy    = wsub >> 1;    // w 32-half
  unsigned wx    = wsub & 1u;    // d 64-half
  unsigned quad  = lane >> 4;
  unsigned l16   = lane & 15u;
  unsigned tid_g = tid & 255u;   // within group
  unsigned wst   = tid_g & 63u;  // staging w
  unsigned g8    = tid_g >> 6;   // staging c-octet
  f16* Ag = Alds + group * (64u * ALDS_STR);

  unsigned cbase = group * 32u + g8 * 8u;          // 8 staged c's
  const float* prow0 = p5 + (size_t)cbase * (21u * 4096u) + h * 64u + wst;

  f32x4 acc[2][4] = {};
  f16 xv[8]; float pv[8];

  // prologue: load chunk j=0 (rk=0 -> r=0, kc=0)
  {
    const f16* xrow = xk + (((size_t)(0u * 4u + n) * 128u + cbase) * XROWS + (h + 0u)) * 64u + wst;
    const float* prow = prow0 + 0u * 4096u;
#pragma unroll
    for (int i = 0; i < 8; i++) {
      xv[i] = xrow[(size_t)i * XSTR];
      pv[i] = prow[(size_t)i * (21u * 4096u)];
    }
  }

  for (unsigned j = 0; j < 21u; j++) {
    __syncthreads();   // previous chunk's LDS reads done
    {
      f16x8 av;
#pragma unroll
      for (int i = 0; i < 8; i++) av[i] = (f16)((float)xv[i] * (1.0f + pv[i]));
      *(f16x8*)&Ag[wst * ALDS_STR + g8 * 8u] = av;
    }
    __syncthreads();

    if (j + 1u < 21u) {  // prefetch next chunk: rk=j+1
      unsigned rk = j + 1u;
      unsigned r  = rk / 3u;
      unsigned kc = rk - r * 3u;
      const f16* xrow = xk + (((size_t)(kc * 4u + n) * 128u + cbase) * XROWS + (h + 3u * r)) * 64u + wst;
      const float* prow = prow0 + rk * 4096u;
#pragma unroll
      for (int i = 0; i < 8; i++) {
        xv[i] = xrow[(size_t)i * XSTR];
        pv[i] = prow[(size_t)i * (21u * 4096u)];
      }
    }

    // MFMA on chunk j: k2 = j*128 + group*32 + quad*8
    f16x8 a[2], bf[4];
#pragma unroll
    for (int ms = 0; ms < 2; ms++)
      a[ms] = *(const f16x8*)&Ag[(wy * 32u + (unsigned)ms * 16u + l16) * ALDS_STR + quad * 8u];
    unsigned k2 = j * 128u + group * 32u + quad * 8u;
#pragma unroll
    for (int ns = 0; ns < 4; ns++)
      bf[ns] = *(const f16x8*)(t6T + ((size_t)(n * 128u + wx * 64u + (unsigned)ns * 16u + l16) * 2688u + k2));
#pragma unroll
    for (int ms = 0; ms < 2; ms++)
#pragma unroll
      for (int ns = 0; ns < 4; ns++)
        acc[ms][ns] = __builtin_amdgcn_mfma_f32_16x16x32_f16(a[ms], bf[ns], acc[ms][ns], 0, 0, 0);
  }

  // ---- 4-phase cross-group reduction in LDS (tile Rt[d][w], f32) ----
  __syncthreads();   // staging region dead; safe to alias as Rt
  float* Rt = smem;
  for (unsigned p = 0; p < 4u; p++) {
    if (group == p) {
#pragma unroll
      for (int ms = 0; ms < 2; ms++) {
#pragma unroll
        for (int ns = 0; ns < 4; ns++) {
          unsigned w0 = wy * 32u + (unsigned)ms * 16u + quad * 4u;
          unsigned d  = wx * 64u + (unsigned)ns * 16u + l16;
#pragma unroll
          for (int reg = 0; reg < 4; reg++) {
            unsigned a_ = d * RT_STR + w0 + (unsigned)reg;
            if (p == 0) Rt[a_] = acc[ms][ns][reg];
            else        Rt[a_] += acc[ms][ns][reg];
          }
        }
      }
    }
    __syncthreads();
  }

  // ---- final coalesced store: out[n][d][h][w] ----
  const float FS = 0.15430334996209192f;  // 8 / sqrt(2688)
  unsigned d  = tid >> 3;          // 0..127
  unsigned w0 = (tid & 7u) * 8u;   // 0..56
  f32x4 o0, o1;
#pragma unroll
  for (int i = 0; i < 4; i++) o0[i] = Rt[d * RT_STR + w0 + (unsigned)i] * FS;
#pragma unroll
  for (int i = 0; i < 4; i++) o1[i] = Rt[d * RT_STR + w0 + 4u + (unsigned)i] * FS;
  float* op = out + ((size_t)(n * 128u + d) * 64u + h) * 64u + w0;
  *(f32x4*)op = o0;
  *(f32x4*)(op + 4) = o1;
}

// ---------------------------------------------------------------- launch
extern "C" void kernel_launch(void* const* d_in, const int* in_sizes, int n_in,
                              void* d_out, int out_size, void* d_ws, size_t ws_size,
                              hipStream_t stream) {
  const float* x  = (const float*)d_in[0];
  const float* p5 = (const float*)d_in[1];
  const float* p6 = (const float*)d_in[2];
  float* out = (float*)d_out;
  f16*   xk  = (f16*)((char*)d_ws);
  f16*   t6T = (f16*)((char*)d_ws + T6T_OFF);
  float* t3  = (float*)((char*)d_ws + T3_OFF);

  hipMemsetAsync(t3, 0, T3_BYTES, stream);

  unsigned prep_blocks = (3u * 4u * 128u * 82u * 32u + 255u) / 256u;  // 15744
  hipLaunchKernelGGL(prep_kernel, dim3(prep_blocks), dim3(256), 0, stream, x, xk);
  hipLaunchKernelGGL(gram_kernel, dim3(1344), dim3(256), 0, stream, xk, t3);
  hipLaunchKernelGGL(ep_kernel,   dim3(1344), dim3(256), 0, stream, t3, p6, t6T);
  hipLaunchKernelGGL(out_kernel,  dim3(256),  dim3(1024), 0, stream, xk, p5, t6T, out);
}

// Round 3
// 218.840 us; speedup vs baseline: 1.3253x; 1.0753x over previous
//
#include <hip/hip_runtime.h>

typedef _Float16 f16;
typedef _Float16 f16x2 __attribute__((ext_vector_type(2)));
typedef _Float16 f16x4 __attribute__((ext_vector_type(4)));
typedef _Float16 f16x8 __attribute__((ext_vector_type(8)));
typedef float    f32x4 __attribute__((ext_vector_type(4)));

// Geometry:
//   x:   (4,128,64,64) f32     p5: (128,21,64,64) f32
//   p6:  (128,21,128)  f32     out:(4,128,64,64)  f32
// Workspace layout:
//   xk  [3][4][128][82][64] f16  = x*(1/8), pre-shifted per kc, zero-padded rows
//   t6T [4][128][2688]      f16  = p6 * t3, d-major (B^T for out GEMM)
//   t3p [8][4][21][128][128] f16 = split-K partial Gram slices (ks = h/8)
#define XROWS 82
#define XSTR  (XROWS * 64)                       // 5248 f16 per (kc,n,c) plane
#define XK_ELEMS (3u * 4u * 128u * (unsigned)XSTR)
static const size_t T6T_OFF   = (size_t)XK_ELEMS * 2;                // 16.1 MB
static const size_t T6T_BYTES = (size_t)4 * 128 * 2688 * 2;          // 2.75 MB
static const size_t T3P_OFF   = T6T_OFF + T6T_BYTES;
// t3p: 8*4*21*128*128 f16 = 22 MB

// ---------------------------------------------------------------- prep
__global__ __launch_bounds__(256) void prep_kernel(const float* __restrict__ x,
                                                   f16* __restrict__ xk) {
  unsigned p = blockIdx.x * 256u + threadIdx.x;           // f16x2 index
  unsigned total = 3u * 4u * 128u * 82u * 32u;
  if (p >= total) return;
  unsigned wp   = p & 31u;
  unsigned row  = (p >> 5) % 82u;
  unsigned rest = p / (32u * 82u);
  unsigned c    = rest & 127u;
  unsigned rest2 = rest >> 7;
  unsigned n    = rest2 & 3u;
  unsigned kc   = rest2 >> 2;
  int hsrc = (int)row - 9;
  int wsrc = (int)(wp * 2u) + 2 * (int)kc - 2;
  f16x2 v; v.x = (f16)0.f; v.y = (f16)0.f;
  if (hsrc >= 0 && hsrc < 64 && wsrc >= 0 && wsrc < 64) {
    const float2* src = (const float2*)(x + (((size_t)(n * 128u + c) * 64u + (unsigned)hsrc) * 64u + (unsigned)wsrc));
    float2 xv = *src;
    v.x = (f16)(xv.x * 0.125f);
    v.y = (f16)(xv.y * 0.125f);
  }
  ((f16x2*)xk)[p] = v;
}

// ---------------------------------------------------------------- gram (split-K -> f16 partial slices)
// grid 1344 = n(4)*rk(21)*cseg(2)*ks(8); block 256 (4 waves 2x2), tile 64c x 128d, K-slice = 8 h rows
__global__ __launch_bounds__(256, 4) void gram_kernel(const f16* __restrict__ xk,
                                                      f16* __restrict__ t3p) {
  unsigned b    = blockIdx.x;
  unsigned ks   = b & 7u;
  unsigned cseg = (b >> 3) & 1u;
  unsigned rk   = (b >> 4) % 21u;
  unsigned n    = b / (16u * 21u);
  unsigned r    = rk / 3u;
  unsigned kc   = rk - r * 3u;

  unsigned tid  = threadIdx.x;
  unsigned wv   = tid >> 6;
  unsigned lane = tid & 63u;
  unsigned wy   = wv >> 1;      // c 32-half within cseg
  unsigned wx   = wv & 1u;      // d 64-half
  unsigned quad = lane >> 4;
  unsigned l16  = lane & 15u;

  f32x4 acc[2][4] = {};

  const f16* Abase = xk + (size_t)(kc * 4u + n) * 128u * XSTR;
  const f16* Bbase = xk + (size_t)(1u * 4u + n) * 128u * XSTR;
  unsigned cA = cseg * 64u + wy * 32u + l16;
  unsigned dB = wx * 64u + l16;
  unsigned h0 = ks * 8u;
  unsigned abase = (h0 + 3u * r) * 64u + quad * 8u;
  unsigned bbase = (h0 + 9u) * 64u + quad * 8u;
  const f16* Ap[2];
  const f16* Bp[4];
#pragma unroll
  for (int ms = 0; ms < 2; ms++) Ap[ms] = Abase + (size_t)(cA + ms * 16u) * XSTR + abase;
#pragma unroll
  for (int ns = 0; ns < 4; ns++) Bp[ns] = Bbase + (size_t)(dB + ns * 16u) * XSTR + bbase;

  // 16 K-steps of 32 (8 h-rows x 2 half-rows); offset advances +32 each step.
  // Explicit 2-slot pipeline; full unroll lets the allocator deepen MLP to the VGPR cap.
  f16x8 fa[2][2], fb[2][4];
#pragma unroll
  for (int ms = 0; ms < 2; ms++) fa[0][ms] = *(const f16x8*)(Ap[ms]);
#pragma unroll
  for (int ns = 0; ns < 4; ns++) fb[0][ns] = *(const f16x8*)(Bp[ns]);

#pragma unroll
  for (unsigned s = 0; s < 16u; s++) {
    unsigned cur = s & 1u, nxt = cur ^ 1u;
    if (s < 15u) {
      unsigned off = 32u * (s + 1u);
#pragma unroll
      for (int ms = 0; ms < 2; ms++) fa[nxt][ms] = *(const f16x8*)(Ap[ms] + off);
#pragma unroll
      for (int ns = 0; ns < 4; ns++) fb[nxt][ns] = *(const f16x8*)(Bp[ns] + off);
    }
#pragma unroll
    for (int ms = 0; ms < 2; ms++)
#pragma unroll
      for (int ns = 0; ns < 4; ns++)
        acc[ms][ns] = __builtin_amdgcn_mfma_f32_16x16x32_f16(fa[cur][ms], fb[cur][ns], acc[ms][ns], 0, 0, 0);
  }

  // plain f16 partial store: t3p[ks][n][rk][c][d]
  f16* tp = t3p + ((size_t)(ks * 4u + n) * 21u + rk) * 16384u;
#pragma unroll
  for (int ms = 0; ms < 2; ms++) {
#pragma unroll
    for (int ns = 0; ns < 4; ns++) {
      unsigned c0 = cseg * 64u + wy * 32u + (unsigned)ms * 16u + quad * 4u;
      unsigned d  = wx * 64u + (unsigned)ns * 16u + l16;
#pragma unroll
      for (int reg = 0; reg < 4; reg++)
        tp[(size_t)(c0 + (unsigned)reg) * 128u + d] = (f16)acc[ms][ns][reg];
    }
  }
}

// ---------------------------------------------------------------- ep: t6T = p6 * sum_ks(t3p)
// grid 1344*256 threads; thread = (n,rk,c, d-quad): coalesced f16x4 slice reads
__global__ __launch_bounds__(256) void ep_kernel(const f16* __restrict__ t3p,
                                                 const float* __restrict__ p6,
                                                 f16* __restrict__ t6T) {
  unsigned idx = blockIdx.x * 256u + threadIdx.x;   // < 344064
  unsigned d4  = idx & 31u;                          // d-quad
  unsigned c   = (idx >> 5) & 127u;
  unsigned t   = idx >> 12;                          // n*21+rk
  unsigned rk  = t % 21u;
  unsigned n   = t / 21u;
  unsigned d0  = d4 * 4u;

  float s0 = 0.f, s1 = 0.f, s2 = 0.f, s3 = 0.f;
#pragma unroll
  for (unsigned ks = 0; ks < 8u; ks++) {
    f16x4 v = *(const f16x4*)(t3p + (((size_t)(ks * 4u + n) * 21u + rk) * 16384u + c * 128u + d0));
    s0 += (float)v[0]; s1 += (float)v[1]; s2 += (float)v[2]; s3 += (float)v[3];
  }
  const float* pp = p6 + ((size_t)c * 21u + rk) * 128u + d0;
  f16 o0 = (f16)(s0 * pp[0]);
  f16 o1 = (f16)(s1 * pp[1]);
  f16 o2 = (f16)(s2 * pp[2]);
  f16 o3 = (f16)(s3 * pp[3]);
  f16* ob = t6T + (size_t)(n * 128u + d0) * 2688u + rk * 128u + c;
  ob[0] = o0; ob[2688] = o1; ob[2 * 2688] = o2; ob[3 * 2688] = o3;
}

// ---------------------------------------------------------------- out (t8)
// grid 256 = n(4)*h(64); block 1024 = 16 waves = 4 K-groups x 4 waves.
// Double-buffered LDS staging: ONE barrier per chunk; B-fragments prefetched pre-barrier.
#define ALDS_STR 40   // f16 row stride (80 B, 16B-aligned)
#define RT_STR   66   // f32 reduce-tile stride
__global__ __launch_bounds__(1024, 4) void out_kernel(const f16* __restrict__ xk,
                                                      const float* __restrict__ p5,
                                                      const f16* __restrict__ t6T,
                                                      float* __restrict__ out) {
  unsigned b = blockIdx.x;
  unsigned h = b & 63u;
  unsigned n = b >> 6;

  __shared__ float smem[10240];   // 40960 B: 2 staging buffers (2x20480 B); aliased later as Rt (33792 B)
  f16* Alds = (f16*)smem;

  unsigned tid   = threadIdx.x;
  unsigned wv    = tid >> 6;
  unsigned group = wv >> 2;      // K-quarter owner
  unsigned wsub  = wv & 3u;
  unsigned lane  = tid & 63u;
  unsigned wy    = wsub >> 1;    // w 32-half
  unsigned wx    = wsub & 1u;    // d 64-half
  unsigned quad  = lane >> 4;
  unsigned l16   = lane & 15u;
  unsigned tid_g = tid & 255u;
  unsigned wst   = tid_g & 63u;  // staging w
  unsigned g8    = tid_g >> 6;   // staging c-octet

  unsigned cbase = group * 32u + g8 * 8u;
  const float* prow0 = p5 + (size_t)cbase * (21u * 4096u) + h * 64u + wst;
  const f16* bfbase = t6T + (size_t)(n * 128u + wx * 64u + l16) * 2688u + group * 32u + quad * 8u;

  f32x4 acc[2][4] = {};
  f16 xv[8]; float pv[8];

  // prologue: chunk j=0 (rk=0 -> r=0, kc=0)
  {
    const f16* xrow = xk + (((size_t)(0u * 4u + n) * 128u + cbase) * XROWS + h) * 64u + wst;
#pragma unroll
    for (int i = 0; i < 8; i++) {
      xv[i] = xrow[(size_t)i * XSTR];
      pv[i] = prow0[(size_t)i * (21u * 4096u)];
    }
  }

  for (unsigned j = 0; j < 21u; j++) {
    unsigned buf = j & 1u;
    f16* Ag = Alds + buf * 10240u + group * 2560u;
    {
      f16x8 av;
#pragma unroll
      for (int i = 0; i < 8; i++) av[i] = (f16)((float)xv[i] * (1.0f + pv[i]));
      *(f16x8*)&Ag[wst * ALDS_STR + g8 * 8u] = av;
    }

    if (j + 1u < 21u) {  // prefetch next chunk's staging operands (independent of LDS)
      unsigned rk = j + 1u;
      unsigned r  = rk / 3u;
      unsigned kc = rk - r * 3u;
      const f16* xrow = xk + (((size_t)(kc * 4u + n) * 128u + cbase) * XROWS + (h + 3u * r)) * 64u + wst;
      const float* prow = prow0 + rk * 4096u;
#pragma unroll
      for (int i = 0; i < 8; i++) {
        xv[i] = xrow[(size_t)i * XSTR];
        pv[i] = prow[(size_t)i * (21u * 4096u)];
      }
    }

    // prefetch B-fragments for chunk j (independent of LDS)
    f16x8 bf[4];
#pragma unroll
    for (int ns = 0; ns < 4; ns++)
      bf[ns] = *(const f16x8*)(bfbase + (size_t)ns * 16u * 2688u + j * 128u);

    __syncthreads();

    f16x8 a[2];
#pragma unroll
    for (int ms = 0; ms < 2; ms++)
      a[ms] = *(const f16x8*)&Ag[(wy * 32u + (unsigned)ms * 16u + l16) * ALDS_STR + quad * 8u];
#pragma unroll
    for (int ms = 0; ms < 2; ms++)
#pragma unroll
      for (int ns = 0; ns < 4; ns++)
        acc[ms][ns] = __builtin_amdgcn_mfma_f32_16x16x32_f16(a[ms], bf[ns], acc[ms][ns], 0, 0, 0);
  }

  // ---- 4-phase cross-group reduction in LDS ----
  __syncthreads();
  float* Rt = smem;
  for (unsigned p = 0; p < 4u; p++) {
    if (group == p) {
#pragma unroll
      for (int ms = 0; ms < 2; ms++) {
#pragma unroll
        for (int ns = 0; ns < 4; ns++) {
          unsigned w0 = wy * 32u + (unsigned)ms * 16u + quad * 4u;
          unsigned d  = wx * 64u + (unsigned)ns * 16u + l16;
#pragma unroll
          for (int reg = 0; reg < 4; reg++) {
            unsigned a_ = d * RT_STR + w0 + (unsigned)reg;
            if (p == 0) Rt[a_] = acc[ms][ns][reg];
            else        Rt[a_] += acc[ms][ns][reg];
          }
        }
      }
    }
    __syncthreads();
  }

  // ---- final coalesced store: out[n][d][h][w] ----
  const float FS = 0.15430334996209192f;  // 8 / sqrt(2688)
  unsigned d  = tid >> 3;
  unsigned w0 = (tid & 7u) * 8u;
  f32x4 o0, o1;
#pragma unroll
  for (int i = 0; i < 4; i++) o0[i] = Rt[d * RT_STR + w0 + (unsigned)i] * FS;
#pragma unroll
  for (int i = 0; i < 4; i++) o1[i] = Rt[d * RT_STR + w0 + 4u + (unsigned)i] * FS;
  float* op = out + ((size_t)(n * 128u + d) * 64u + h) * 64u + w0;
  *(f32x4*)op = o0;
  *(f32x4*)(op + 4) = o1;
}

// ---------------------------------------------------------------- launch
extern "C" void kernel_launch(void* const* d_in, const int* in_sizes, int n_in,
                              void* d_out, int out_size, void* d_ws, size_t ws_size,
                              hipStream_t stream) {
  const float* x  = (const float*)d_in[0];
  const float* p5 = (const float*)d_in[1];
  const float* p6 = (const float*)d_in[2];
  float* out = (float*)d_out;
  f16* xk  = (f16*)((char*)d_ws);
  f16* t6T = (f16*)((char*)d_ws + T6T_OFF);
  f16* t3p = (f16*)((char*)d_ws + T3P_OFF);

  unsigned prep_blocks = (3u * 4u * 128u * 82u * 32u + 255u) / 256u;  // 15744
  hipLaunchKernelGGL(prep_kernel, dim3(prep_blocks), dim3(256), 0, stream, x, xk);
  hipLaunchKernelGGL(gram_kernel, dim3(1344), dim3(256), 0, stream, xk, t3p);
  hipLaunchKernelGGL(ep_kernel,   dim3(1344), dim3(256), 0, stream, t3p, p6, t6T);
  hipLaunchKernelGGL(out_kernel,  dim3(256),  dim3(1024), 0, stream, xk, p5, t6T, out);
}

// Round 4
// 173.723 us; speedup vs baseline: 1.6695x; 1.2597x over previous
//
#include <hip/hip_runtime.h>

typedef _Float16 f16;
typedef _Float16 f16x2 __attribute__((ext_vector_type(2)));
typedef _Float16 f16x4 __attribute__((ext_vector_type(4)));
typedef _Float16 f16x8 __attribute__((ext_vector_type(8)));
typedef float    f32x4 __attribute__((ext_vector_type(4)));

// Geometry:
//   x:   (4,128,64,64) f32     p5: (128,21,64,64) f32
//   p6:  (128,21,128)  f32     out:(4,128,64,64)  f32
// Workspace:
//   xk  [3][4][128][82][64] f16 = x*(1/8), pre-shifted per kc, zero-padded rows
//   t6T [4][128][2688]      f16 = p6 * t3, d-major
//   t3p [8][4][21][128][128] f16 = split-K Gram partials
//   t8p [4][4][64][128][64]  f16 = split-K out partials (g,n,h,d,w)
#define XROWS 82
#define XSTR  (XROWS * 64)
#define XK_ELEMS (3u * 4u * 128u * (unsigned)XSTR)
static const size_t T6T_OFF   = (size_t)XK_ELEMS * 2;
static const size_t T6T_BYTES = (size_t)4 * 128 * 2688 * 2;
static const size_t T3P_OFF   = T6T_OFF + T6T_BYTES;
static const size_t T3P_BYTES = (size_t)8 * 4 * 21 * 128 * 128 * 2;   // 22.0 MB
static const size_t T8P_OFF   = T3P_OFF + T3P_BYTES;

__device__ __forceinline__ void gl16(const f16* g, f16* l) {
  __builtin_amdgcn_global_load_lds((const __attribute__((address_space(1))) void*)g,
                                   (__attribute__((address_space(3))) void*)l, 16, 0, 0);
}

// ---------------------------------------------------------------- prep
__global__ __launch_bounds__(256) void prep_kernel(const float* __restrict__ x,
                                                   f16* __restrict__ xk) {
  unsigned p = blockIdx.x * 256u + threadIdx.x;
  unsigned total = 3u * 4u * 128u * 82u * 32u;
  if (p >= total) return;
  unsigned wp   = p & 31u;
  unsigned row  = (p >> 5) % 82u;
  unsigned rest = p / (32u * 82u);
  unsigned c    = rest & 127u;
  unsigned rest2 = rest >> 7;
  unsigned n    = rest2 & 3u;
  unsigned kc   = rest2 >> 2;
  int hsrc = (int)row - 9;
  int wsrc = (int)(wp * 2u) + 2 * (int)kc - 2;
  f16x2 v; v.x = (f16)0.f; v.y = (f16)0.f;
  if (hsrc >= 0 && hsrc < 64 && wsrc >= 0 && wsrc < 64) {
    const float2* src = (const float2*)(x + (((size_t)(n * 128u + c) * 64u + (unsigned)hsrc) * 64u + (unsigned)wsrc));
    float2 xv = *src;
    v.x = (f16)(xv.x * 0.125f);
    v.y = (f16)(xv.y * 0.125f);
  }
  ((f16x2*)xk)[p] = v;
}

// ---------------------------------------------------------------- gram (LDS-staged, split-K -> f16 partials)
// grid 1344 = n*rk*cseg*ks; block 256 (4 waves 2x2), tile 64c x 128d, K-slice 512, 8 steps of 64.
// A/B step tiles staged via global_load_lds (XOR-swizzled 16B segments), double-buffered.
__global__ __launch_bounds__(256, 3) void gram_kernel(const f16* __restrict__ xk,
                                                      f16* __restrict__ t3p) {
  __shared__ f16 gl[2 * 12288];   // per buf: A 64*64 + B 128*64 f16 (48 KB total)

  unsigned b    = blockIdx.x;
  unsigned ks   = b & 7u;
  unsigned cseg = (b >> 3) & 1u;
  unsigned rk   = (b >> 4) % 21u;
  unsigned n    = b / (16u * 21u);
  unsigned r    = rk / 3u;
  unsigned kc   = rk - r * 3u;

  unsigned tid  = threadIdx.x;
  unsigned wv   = tid >> 6;
  unsigned lane = tid & 63u;
  unsigned wy   = wv >> 1;
  unsigned wx   = wv & 1u;
  unsigned quad = lane >> 4;
  unsigned l16  = lane & 15u;
  unsigned rsl  = lane >> 3;                 // staging row slot 0..7
  unsigned seg  = (lane & 7u) ^ (rsl & 7u);  // swizzled source segment

  unsigned h0 = ks * 8u;
  const f16* Ab = xk + (size_t)(kc * 4u + n) * 128u * XSTR + (size_t)(cseg * 64u) * XSTR
                + (h0 + 3u * r) * 64u + seg * 8u;
  const f16* Bb = xk + (size_t)(4u + n) * 128u * XSTR + (h0 + 9u) * 64u + seg * 8u;
  unsigned ar0 = wv * 16u;   // A rows staged by this wave
  unsigned br0 = wv * 32u;   // B rows staged by this wave

  f32x4 acc[2][4] = {};

  // stage step 0 into buf 0
#pragma unroll
  for (unsigned t = 0; t < 2u; t++)
    gl16(Ab + (size_t)(ar0 + t * 8u + rsl) * XSTR, &gl[(ar0 + t * 8u) * 64u]);
#pragma unroll
  for (unsigned t = 0; t < 4u; t++)
    gl16(Bb + (size_t)(br0 + t * 8u + rsl) * XSTR, &gl[4096u + (br0 + t * 8u) * 64u]);

  for (unsigned s = 0; s < 8u; s++) {
    __syncthreads();   // drains staging for step s (vmcnt0)
    if (s < 7u) {      // fire-and-forget prefetch of step s+1 (overlaps compute below)
      f16* base = &gl[((s + 1u) & 1u) * 12288u];
      unsigned off = (s + 1u) * 64u;
#pragma unroll
      for (unsigned t = 0; t < 2u; t++)
        gl16(Ab + off + (size_t)(ar0 + t * 8u + rsl) * XSTR, base + (ar0 + t * 8u) * 64u);
#pragma unroll
      for (unsigned t = 0; t < 4u; t++)
        gl16(Bb + off + (size_t)(br0 + t * 8u + rsl) * XSTR, base + 4096u + (br0 + t * 8u) * 64u);
    }
    const f16* bufA = &gl[(s & 1u) * 12288u];
    const f16* bufB = bufA + 4096u;
#pragma unroll
    for (unsigned t2 = 0; t2 < 2u; t2++) {
      unsigned L = t2 * 4u + quad;
      f16x8 a[2], bb[4];
#pragma unroll
      for (int ms = 0; ms < 2; ms++) {
        unsigned rr = wy * 32u + (unsigned)ms * 16u + l16;
        a[ms] = *(const f16x8*)&bufA[rr * 64u + (L ^ (rr & 7u)) * 8u];
      }
#pragma unroll
      for (int ns = 0; ns < 4; ns++) {
        unsigned rb = wx * 64u + (unsigned)ns * 16u + l16;
        bb[ns] = *(const f16x8*)&bufB[rb * 64u + (L ^ (rb & 7u)) * 8u];
      }
#pragma unroll
      for (int ms = 0; ms < 2; ms++)
#pragma unroll
        for (int ns = 0; ns < 4; ns++)
          acc[ms][ns] = __builtin_amdgcn_mfma_f32_16x16x32_f16(a[ms], bb[ns], acc[ms][ns], 0, 0, 0);
    }
  }

  // f16 partial store: t3p[ks][n][rk][c][d]
  f16* tp = t3p + ((size_t)(ks * 4u + n) * 21u + rk) * 16384u;
#pragma unroll
  for (int ms = 0; ms < 2; ms++) {
#pragma unroll
    for (int ns = 0; ns < 4; ns++) {
      unsigned c0 = cseg * 64u + wy * 32u + (unsigned)ms * 16u + quad * 4u;
      unsigned d  = wx * 64u + (unsigned)ns * 16u + l16;
#pragma unroll
      for (int reg = 0; reg < 4; reg++)
        tp[(size_t)(c0 + (unsigned)reg) * 128u + d] = (f16)acc[ms][ns][reg];
    }
  }
}

// ---------------------------------------------------------------- ep: t6T = p6 * sum_ks(t3p)
__global__ __launch_bounds__(256) void ep_kernel(const f16* __restrict__ t3p,
                                                 const float* __restrict__ p6,
                                                 f16* __restrict__ t6T) {
  unsigned idx = blockIdx.x * 256u + threadIdx.x;   // < 344064
  unsigned d4  = idx & 31u;
  unsigned c   = (idx >> 5) & 127u;
  unsigned t   = idx >> 12;
  unsigned rk  = t % 21u;
  unsigned n   = t / 21u;
  unsigned d0  = d4 * 4u;

  float s0 = 0.f, s1 = 0.f, s2 = 0.f, s3 = 0.f;
#pragma unroll
  for (unsigned ks = 0; ks < 8u; ks++) {
    f16x4 v = *(const f16x4*)(t3p + (((size_t)(ks * 4u + n) * 21u + rk) * 16384u + c * 128u + d0));
    s0 += (float)v[0]; s1 += (float)v[1]; s2 += (float)v[2]; s3 += (float)v[3];
  }
  const float* pp = p6 + ((size_t)c * 21u + rk) * 128u + d0;
  f16 o0 = (f16)(s0 * pp[0]);
  f16 o1 = (f16)(s1 * pp[1]);
  f16 o2 = (f16)(s2 * pp[2]);
  f16 o3 = (f16)(s3 * pp[3]);
  f16* ob = t6T + (size_t)(n * 128u + d0) * 2688u + rk * 128u + c;
  ob[0] = o0; ob[2688] = o1; ob[2 * 2688] = o2; ob[3 * 2688] = o3;
}

// ---------------------------------------------------------------- outp (t8 split-K x4)
// grid 1024 = n(4)*h(64)*g(4); block 256 (4 waves 2x2), tile 64w x 128d.
// Group g owns c-quarter [g*32,g*32+32) of all 21 rk chunks. f16 partials via LDS transpose.
#define ALDS_STR 40
#define RT_STR   66
__global__ __launch_bounds__(256, 4) void outp_kernel(const f16* __restrict__ xk,
                                                      const float* __restrict__ p5,
                                                      const f16* __restrict__ t6T,
                                                      f16* __restrict__ t8p) {
  __shared__ float smem[8448];    // 33792 B; first 10240 B = 2 staging bufs, aliased as Rt later
  f16* Alds = (f16*)smem;

  unsigned b = blockIdx.x;
  unsigned g = b & 3u;
  unsigned h = (b >> 2) & 63u;
  unsigned n = b >> 8;

  unsigned tid  = threadIdx.x;
  unsigned wv   = tid >> 6;
  unsigned lane = tid & 63u;
  unsigned wy   = wv >> 1;
  unsigned wx   = wv & 1u;
  unsigned quad = lane >> 4;
  unsigned l16  = lane & 15u;
  unsigned wst  = tid & 63u;
  unsigned g8   = tid >> 6;

  unsigned cbase = g * 32u + g8 * 8u;
  const float* prow0 = p5 + (size_t)cbase * (21u * 4096u) + h * 64u + wst;
  const f16* bfb = t6T + (size_t)(n * 128u + wx * 64u + l16) * 2688u + g * 32u + quad * 8u;

  f32x4 acc[2][4] = {};
  f16 xv[8]; float pv[8];
  f16x8 bfc[4];

  { // prefetch chunk 0 (rk=0 -> r=0, kc=0)
    const f16* xrow = xk + (((size_t)n * 128u + cbase) * XROWS + h) * 64u + wst;
#pragma unroll
    for (int i = 0; i < 8; i++) { xv[i] = xrow[(size_t)i * XSTR]; pv[i] = prow0[(size_t)i * (21u * 4096u)]; }
#pragma unroll
    for (int ns = 0; ns < 4; ns++) bfc[ns] = *(const f16x8*)(bfb + (size_t)ns * 16u * 2688u);
  }

  for (unsigned j = 0; j < 21u; j++) {
    f16* Ag = Alds + (j & 1u) * 2560u;
    {
      f16x8 av;
#pragma unroll
      for (int i = 0; i < 8; i++) av[i] = (f16)((float)xv[i] * (1.0f + pv[i]));
      *(f16x8*)&Ag[wst * ALDS_STR + g8 * 8u] = av;
    }
    __syncthreads();

    f16x8 bfn[4];
    if (j < 20u) {   // register prefetch of chunk j+1 (overlaps MFMA below)
      unsigned rk = j + 1u;
      unsigned rr = rk / 3u;
      unsigned kcc = rk - rr * 3u;
      const f16* xrow = xk + (((size_t)(kcc * 4u + n) * 128u + cbase) * XROWS + (h + 3u * rr)) * 64u + wst;
      const float* prow = prow0 + rk * 4096u;
#pragma unroll
      for (int i = 0; i < 8; i++) { xv[i] = xrow[(size_t)i * XSTR]; pv[i] = prow[(size_t)i * (21u * 4096u)]; }
#pragma unroll
      for (int ns = 0; ns < 4; ns++) bfn[ns] = *(const f16x8*)(bfb + (size_t)ns * 16u * 2688u + rk * 128u);
    }

    f16x8 a[2];
#pragma unroll
    for (int ms = 0; ms < 2; ms++)
      a[ms] = *(const f16x8*)&Ag[(wy * 32u + (unsigned)ms * 16u + l16) * ALDS_STR + quad * 8u];
#pragma unroll
    for (int ms = 0; ms < 2; ms++)
#pragma unroll
      for (int ns = 0; ns < 4; ns++)
        acc[ms][ns] = __builtin_amdgcn_mfma_f32_16x16x32_f16(a[ms], bfc[ns], acc[ms][ns], 0, 0, 0);
#pragma unroll
    for (int ns = 0; ns < 4; ns++) bfc[ns] = bfn[ns];
  }

  // transpose via LDS for coalesced f16 partial stores: t8p[g][n][h][d][w]
  __syncthreads();
  float* Rt = smem;
#pragma unroll
  for (int ms = 0; ms < 2; ms++)
#pragma unroll
    for (int ns = 0; ns < 4; ns++) {
      unsigned w0 = wy * 32u + (unsigned)ms * 16u + quad * 4u;
      unsigned d  = wx * 64u + (unsigned)ns * 16u + l16;
#pragma unroll
      for (int reg = 0; reg < 4; reg++)
        Rt[d * RT_STR + w0 + (unsigned)reg] = acc[ms][ns][reg];
    }
  __syncthreads();
  f16* op = t8p + ((size_t)((g * 4u + n) * 64u + h)) * 8192u;
#pragma unroll
  for (unsigned it = 0; it < 4u; it++) {
    unsigned row = (tid >> 3) + it * 32u;
    unsigned w0  = (tid & 7u) * 8u;
    f16x8 o;
#pragma unroll
    for (int i = 0; i < 8; i++) o[i] = (f16)Rt[row * RT_STR + w0 + (unsigned)i];
    *(f16x8*)(op + row * 64u + w0) = o;
  }
}

// ---------------------------------------------------------------- red: out = FS * sum_g(t8p)
__global__ __launch_bounds__(256) void red_kernel(const f16* __restrict__ t8p,
                                                  float* __restrict__ out) {
  unsigned idx = blockIdx.x * 256u + threadIdx.x;   // < 262144
  unsigned w0 = (idx & 7u) * 8u;
  unsigned h  = (idx >> 3) & 63u;
  unsigned d  = (idx >> 9) & 127u;
  unsigned n  = idx >> 16;
  const float FS = 0.15430334996209192f;  // 8 / sqrt(2688)
  float s[8] = {};
#pragma unroll
  for (unsigned g = 0; g < 4u; g++) {
    f16x8 v = *(const f16x8*)(t8p + ((size_t)((g * 4u + n) * 64u + h)) * 8192u + d * 64u + w0);
#pragma unroll
    for (int i = 0; i < 8; i++) s[i] += (float)v[i];
  }
  f32x4 o0, o1;
#pragma unroll
  for (int i = 0; i < 4; i++) { o0[i] = s[i] * FS; o1[i] = s[i + 4] * FS; }
  float* op = out + ((size_t)(n * 128u + d) * 64u + h) * 64u + w0;
  *(f32x4*)op = o0;
  *(f32x4*)(op + 4) = o1;
}

// ---------------------------------------------------------------- launch
extern "C" void kernel_launch(void* const* d_in, const int* in_sizes, int n_in,
                              void* d_out, int out_size, void* d_ws, size_t ws_size,
                              hipStream_t stream) {
  const float* x  = (const float*)d_in[0];
  const float* p5 = (const float*)d_in[1];
  const float* p6 = (const float*)d_in[2];
  float* out = (float*)d_out;
  f16* xk  = (f16*)((char*)d_ws);
  f16* t6T = (f16*)((char*)d_ws + T6T_OFF);
  f16* t3p = (f16*)((char*)d_ws + T3P_OFF);
  f16* t8p = (f16*)((char*)d_ws + T8P_OFF);

  unsigned prep_blocks = (3u * 4u * 128u * 82u * 32u + 255u) / 256u;  // 15744
  hipLaunchKernelGGL(prep_kernel, dim3(prep_blocks), dim3(256), 0, stream, x, xk);
  hipLaunchKernelGGL(gram_kernel, dim3(1344), dim3(256), 0, stream, xk, t3p);
  hipLaunchKernelGGL(ep_kernel,   dim3(1344), dim3(256), 0, stream, t3p, p6, t6T);
  hipLaunchKernelGGL(outp_kernel, dim3(1024), dim3(256), 0, stream, xk, p5, t6T, t8p);
  hipLaunchKernelGGL(red_kernel,  dim3(1024), dim3(256), 0, stream, t8p, out);
}